// Round 1
// baseline (108.662 us; speedup 1.0000x reference)
//
#include <hip/hip_runtime.h>
#include <hip/hip_fp16.h>
#include <cstdint>

// Problem constants
#define B_TOT  65536
#define D_TOT  256
#define H_SUB  16

// Table config: per-feature piecewise-linear LUT over x in [-8, 8]
#define TBL_N      512
#define TBL_XMIN   (-8.0f)
#define TBL_RANGE  16.0f
#define TBL_DELTA  (TBL_RANGE / (float)TBL_N)          // 0.03125
#define INV_DELTA  ((float)TBL_N / TBL_RANGE)          // 32.0
#define T_OFF      (-(TBL_XMIN) * INV_DELTA)           // 256.0

// Main-kernel tiling
#define DG      32                 // features per group
#define NG      (D_TOT / DG)       // 8 groups
#define BCHUNK  1024               // rows per block
#define NTH     256

__device__ __forceinline__ float tanh_fast(float z) {
    // tanh(z) = 1 - 2/(exp(2z)+1); exp(2z) = exp2(z * 2*log2(e))
    float e = __builtin_amdgcn_exp2f(z * 2.8853900817779268f);
    return 1.0f - 2.0f * __builtin_amdgcn_rcpf(e + 1.0f);
    // z -> -inf: e=0 -> -1 ; z -> +inf: e=inf -> 1. No overflow for |z|<=9.
}

// ---------------------------------------------------------------------------
// Kernel 1: build per-feature LUTs. tab[d*TBL_N + i] = half2(f_d(x_i),
// f_d(x_{i+1}) - f_d(x_i)), where f_d(x) = b2[d] + sum_h w2[d,h]*tanh(w1[d,h]*x+b1[d,h])
// (the b2 bias is folded into the value; it cancels in the slope).
// ---------------------------------------------------------------------------
__global__ void build_tables(const float* __restrict__ w1,
                             const float* __restrict__ b1,
                             const float* __restrict__ w2,
                             const float* __restrict__ b2,
                             uint32_t* __restrict__ tab) {
    int gid = blockIdx.x * NTH + threadIdx.x;      // 0 .. D_TOT*TBL_N-1
    int d = gid >> 9;                              // TBL_N == 512
    int i = gid & (TBL_N - 1);
    float x0 = TBL_XMIN + (float)i * TBL_DELTA;
    float x1 = x0 + TBL_DELTA;
    float f0 = 0.0f, f1 = 0.0f;
#pragma unroll
    for (int h = 0; h < H_SUB; ++h) {
        float a = w1[d * H_SUB + h];
        float c = b1[d * H_SUB + h];
        float w = w2[d * H_SUB + h];
        f0 += w * tanh_fast(fmaf(a, x0, c));
        f1 += w * tanh_fast(fmaf(a, x1, c));
    }
    float val = f0 + b2[d];
    float slp = f1 - f0;
    __half2 h2 = __halves2half2(__float2half_rn(val), __float2half_rn(slp));
    tab[gid] = *reinterpret_cast<uint32_t*>(&h2);
}

// ---------------------------------------------------------------------------
// Kernel 2: streaming gather. Block = (feature-group g, row-chunk bc).
// Thread owns a row b, loops its 32 features, LDS LUT interp, one atomicAdd.
// ---------------------------------------------------------------------------
__global__ __launch_bounds__(NTH, 2) void kan_forward(
        const float* __restrict__ x,
        const uint32_t* __restrict__ tab,
        float* __restrict__ out) {
    __shared__ uint32_t sT[DG * TBL_N];            // 64 KiB -> 2 blocks/CU

    const int g  = blockIdx.x & (NG - 1);
    const int bc = blockIdx.x >> 3;                // NG == 8

    // Coalesced table fill (16 KB per thread-sweep, uint4 vectorized)
    {
        const uint4* src = reinterpret_cast<const uint4*>(tab + g * DG * TBL_N);
        uint4* dst = reinterpret_cast<uint4*>(sT);
#pragma unroll
        for (int k = 0; k < (DG * TBL_N / 4) / NTH; ++k)
            dst[threadIdx.x + k * NTH] = src[threadIdx.x + k * NTH];
    }
    __syncthreads();

    const int b0 = bc * BCHUNK + threadIdx.x;
#pragma unroll
    for (int bi = 0; bi < BCHUNK / NTH; ++bi) {
        const int b = b0 + bi * NTH;
        const float4* xr =
            reinterpret_cast<const float4*>(x + (size_t)b * D_TOT + g * DG);
        float acc = 0.0f;
#pragma unroll
        for (int j = 0; j < DG / 4; ++j) {
            float4 xv = xr[j];
            float vv[4] = {xv.x, xv.y, xv.z, xv.w};
#pragma unroll
            for (int c = 0; c < 4; ++c) {
                float t = fmaf(vv[c], INV_DELTA, T_OFF);
                t = fminf(fmaxf(t, 0.0f), (float)(TBL_N - 1));
                float fi = floorf(t);
                float u = t - fi;
                uint32_t e = sT[(j * 4 + c) * TBL_N + (int)fi];
                union { uint32_t u32; __half2 h2; } cvt;
                cvt.u32 = e;
                acc += fmaf(__high2float(cvt.h2), u, __low2float(cvt.h2));
            }
        }
        atomicAdd(&out[b], acc);
    }
}

extern "C" void kernel_launch(void* const* d_in, const int* in_sizes, int n_in,
                              void* d_out, int out_size, void* d_ws, size_t ws_size,
                              hipStream_t stream) {
    const float* x  = (const float*)d_in[0];
    const float* w1 = (const float*)d_in[1];
    const float* b1 = (const float*)d_in[2];
    const float* w2 = (const float*)d_in[3];
    const float* b2 = (const float*)d_in[4];
    float* out = (float*)d_out;
    uint32_t* tab = (uint32_t*)d_ws;               // needs D_TOT*TBL_N*4 = 512 KiB

    // d_out is poisoned before every timed launch; atomics need zeros.
    hipMemsetAsync(d_out, 0, (size_t)out_size * sizeof(float), stream);

    build_tables<<<dim3(D_TOT * TBL_N / NTH), dim3(NTH), 0, stream>>>(
        w1, b1, w2, b2, tab);

    kan_forward<<<dim3((B_TOT / BCHUNK) * NG), dim3(NTH), 0, stream>>>(
        x, tab, out);
}